// Round 5
// baseline (522.017 us; speedup 1.0000x reference)
//
#include <hip/hip_runtime.h>
#include <hip/hip_cooperative_groups.h>
#include <hip/hip_bf16.h>
#include <cstddef>
#include <cstdint>

namespace cg = cooperative_groups;

#define B_  8
#define S_  32
#define BT_ 256      // B*S
#define N_  2000
#define E_  64000
#define GH_ 32
#define H_  64
#define G4_ 256      // 4*H
#define D_  64000    // N*GH
#define NEG_SLOPE_ 0.2f
#define KC_  32      // split-K chunks in mfma phase (grid = 8 * 32 = 256 blocks)

typedef __attribute__((ext_vector_type(8))) _Float16 half8;
typedef __attribute__((ext_vector_type(4))) float floatx4;

struct KParams {
  const float* x; const int* ei;
  const float* w_lin; const float* att_src; const float* att_dst; const float* gat_bias;
  const float* W_ih; const float* W_hh; const float* b_ih; const float* b_hh;
  const float* W_head; const float* b_head;
  float* out;
  float* xT; float* agg; float* pre_gates; float* hT;
  int* deg; int* rowptr; int* cursor; int* csr_src;
  float* partial;
};

__device__ __forceinline__ float fsigmoid(float x) { return 1.0f / (1.0f + __expf(-x)); }
__device__ __forceinline__ float ftanh_(float x)   { return 1.0f - 2.0f / (__expf(2.0f * x) + 1.0f); }

// ---------------- phase: zero degree array ----------------
__device__ __forceinline__ void ph_zero(const KParams& p) {
  const int gtid = blockIdx.x * 256 + threadIdx.x;
  if (gtid < N_) p.deg[gtid] = 0;
}

// ---------------- phase: transpose x [bt][n] -> xT [n][bt] ----------------
__device__ __forceinline__ void ph_transpose(const KParams& p) {
  __shared__ float tile[32][33];
  const int TXT = (N_ + 31) / 32;  // 63
  const int tx = threadIdx.x & 31;
  const int ty = threadIdx.x >> 5;
  for (int t = blockIdx.x; t < TXT * (BT_ / 32); t += gridDim.x) {
    const int n0  = (t % TXT) * 32;
    const int bt0 = (t / TXT) * 32;
#pragma unroll
    for (int r = 0; r < 4; ++r) {
      const int bt = bt0 + ty + r * 8;
      const int nn = n0 + tx;
      if (nn < N_) tile[ty + r * 8][tx] = p.x[(size_t)bt * N_ + nn];
    }
    __syncthreads();
#pragma unroll
    for (int r = 0; r < 4; ++r) {
      const int n = n0 + ty + r * 8;
      if (n < N_) p.xT[(size_t)n * BT_ + bt0 + tx] = tile[tx][ty + r * 8];
    }
    __syncthreads();
  }
}

// ---------------- phase: degree histogram by dst ----------------
__device__ __forceinline__ void ph_hist(const KParams& p) {
  const int gs = gridDim.x * 256;
  for (int i = blockIdx.x * 256 + threadIdx.x; i < E_; i += gs)
    atomicAdd(&p.deg[p.ei[E_ + i]], 1);
}

// ---------------- phase: exclusive scan (call from ONE block only) --------
__device__ __forceinline__ void ph_scan(const KParams& p) {
  __shared__ int tsum[256];
  const int tid = threadIdx.x;
  int v[8];
  int s = 0;
  const int base = tid * 8;
#pragma unroll
  for (int j = 0; j < 8; ++j) {
    const int idx = base + j;
    const int d = (idx < N_) ? p.deg[idx] : 0;
    v[j] = s;
    s += d;
  }
  tsum[tid] = s;
  __syncthreads();
  for (int off = 1; off < 256; off <<= 1) {
    int t = 0;
    if (tid >= off) t = tsum[tid - off];
    __syncthreads();
    tsum[tid] += t;
    __syncthreads();
  }
  const int ebase = tsum[tid] - s;
#pragma unroll
  for (int j = 0; j < 8; ++j) {
    const int idx = base + j;
    if (idx < N_) {
      const int r = ebase + v[j];
      p.rowptr[idx] = r;
      p.cursor[idx] = r;
    }
  }
  if (tid == 0) p.rowptr[N_] = E_;
}

// ---------------- phase: scatter src ids into CSR buckets ----------------
__device__ __forceinline__ void ph_scatter(const KParams& p) {
  const int gs = gridDim.x * 256;
  for (int i = blockIdx.x * 256 + threadIdx.x; i < E_; i += gs) {
    const int s = p.ei[i];
    const int d = p.ei[E_ + i];
    const int pos = atomicAdd(&p.cursor[d], 1);
    p.csr_src[pos] = s;
  }
}

// ---------------- phase: CSR gather-aggregate -> agg fp32 [n][bt] ---------
__device__ __forceinline__ void ph_gather(const KParams& p) {
  const int tid = threadIdx.x;
  float c_s = 0.f, c_d = 0.f;
  for (int g = 0; g < GH_; ++g) {
    const float w = p.w_lin[g];
    c_s += w * p.att_src[g];
    c_d += w * p.att_dst[g];
  }
  for (int n = blockIdx.x; n < N_; n += gridDim.x) {
    const int r0 = p.rowptr[n];
    const int d  = p.rowptr[n + 1] - r0;
    const float xn = p.xT[(size_t)n * BT_ + tid];
    const float cdxn = c_d * xn;
    float e = (c_s + c_d) * xn;
    e = e > 0.f ? e : NEG_SLOPE_ * e;
    const float w0 = __expf(e);
    float num = w0 * xn, den = w0;
    int pp = 0;
    for (; pp + 4 <= d; pp += 4) {   // unroll-4: 4 independent L2 loads in flight
      const int s0 = p.csr_src[r0 + pp + 0];
      const int s1 = p.csr_src[r0 + pp + 1];
      const int s2 = p.csr_src[r0 + pp + 2];
      const int s3 = p.csr_src[r0 + pp + 3];
      const float x0 = p.xT[(size_t)s0 * BT_ + tid];
      const float x1 = p.xT[(size_t)s1 * BT_ + tid];
      const float x2 = p.xT[(size_t)s2 * BT_ + tid];
      const float x3 = p.xT[(size_t)s3 * BT_ + tid];
      float e0 = fmaf(c_s, x0, cdxn); e0 = e0 > 0.f ? e0 : NEG_SLOPE_ * e0;
      float e1 = fmaf(c_s, x1, cdxn); e1 = e1 > 0.f ? e1 : NEG_SLOPE_ * e1;
      float e2 = fmaf(c_s, x2, cdxn); e2 = e2 > 0.f ? e2 : NEG_SLOPE_ * e2;
      float e3 = fmaf(c_s, x3, cdxn); e3 = e3 > 0.f ? e3 : NEG_SLOPE_ * e3;
      const float w0_ = __expf(e0), w1_ = __expf(e1), w2_ = __expf(e2), w3_ = __expf(e3);
      num += w0_ * x0 + w1_ * x1 + w2_ * x2 + w3_ * x3;
      den += (w0_ + w1_) + (w2_ + w3_);
    }
    for (; pp < d; ++pp) {
      const int s = p.csr_src[r0 + pp];
      const float xs = p.xT[(size_t)s * BT_ + tid];
      float ee = fmaf(c_s, xs, cdxn);
      ee = ee > 0.f ? ee : NEG_SLOPE_ * ee;
      const float ww = __expf(ee);
      num += ww * xs;
      den += ww;
    }
    p.agg[(size_t)n * BT_ + tid] = num / den;
  }
}

// ---------------- phase: fp16 MFMA matmul, split-K -> partial -------------
// pre_gates[bt,j] = sum_{n,gh} W_ih[j, n*32+gh] * relu(agg[bt,n]*wl[gh]+gb[gh])
// job = nb(8 gate-blocks of 32) x kc(32 K-chunks of ~62 nodes). M=256 per block.
__device__ __forceinline__ void ph_mfma(const KParams& p, int job) {
  const int nb = job & 7;
  const int kc = job >> 3;
  const int n0 = (N_ * kc) / KC_;
  const int n1 = (N_ * (kc + 1)) / KC_;
  const int tid  = threadIdx.x;
  const int wv   = tid >> 6;
  const int lane = tid & 63;
  const int i16  = lane & 15;
  const int q    = lane >> 4;
  const int j0   = nb * 32;

  float wlq[8], gbq[8];
#pragma unroll
  for (int j = 0; j < 8; ++j) {
    wlq[j] = p.w_lin[q * 8 + j];
    gbq[j] = p.gat_bias[q * 8 + j];
  }

  floatx4 acc[4][2];
#pragma unroll
  for (int mt = 0; mt < 4; ++mt)
#pragma unroll
    for (int nt = 0; nt < 2; ++nt)
#pragma unroll
      for (int r = 0; r < 4; ++r) acc[mt][nt][r] = 0.f;

  const float* Bp0 = p.W_ih + (size_t)(j0 + i16) * D_ + (size_t)n0 * GH_ + q * 8;
  const float* Bp1 = Bp0 + (size_t)16 * D_;

  float4 c0a = *(const float4*)(Bp0);
  float4 c0b = *(const float4*)(Bp0 + 4);
  float4 c1a = *(const float4*)(Bp1);
  float4 c1b = *(const float4*)(Bp1 + 4);

#pragma unroll 1
  for (int nn = n0; nn < n1; ++nn) {
    const int nx = (nn + 1 < n1) ? (nn + 1 - n0) : (nn - n0);
    const int off = nx * GH_;
    float4 p0a = *(const float4*)(Bp0 + off);
    float4 p0b = *(const float4*)(Bp0 + off + 4);
    float4 p1a = *(const float4*)(Bp1 + off);
    float4 p1b = *(const float4*)(Bp1 + off + 4);

    half8 bf0, bf1;
    bf0[0] = (_Float16)c0a.x; bf0[1] = (_Float16)c0a.y;
    bf0[2] = (_Float16)c0a.z; bf0[3] = (_Float16)c0a.w;
    bf0[4] = (_Float16)c0b.x; bf0[5] = (_Float16)c0b.y;
    bf0[6] = (_Float16)c0b.z; bf0[7] = (_Float16)c0b.w;
    bf1[0] = (_Float16)c1a.x; bf1[1] = (_Float16)c1a.y;
    bf1[2] = (_Float16)c1a.z; bf1[3] = (_Float16)c1a.w;
    bf1[4] = (_Float16)c1b.x; bf1[5] = (_Float16)c1b.y;
    bf1[6] = (_Float16)c1b.z; bf1[7] = (_Float16)c1b.w;

    const float* Ab = p.agg + (size_t)nn * BT_ + wv * 64 + i16;
#pragma unroll
    for (int mt = 0; mt < 4; ++mt) {
      const float a = Ab[mt * 16];
      half8 af;
#pragma unroll
      for (int j = 0; j < 8; ++j) {
        float v = fmaf(a, wlq[j], gbq[j]);
        v = fmaxf(v, 0.f);
        af[j] = (_Float16)v;
      }
      acc[mt][0] = __builtin_amdgcn_mfma_f32_16x16x32_f16(af, bf0, acc[mt][0], 0, 0, 0);
      acc[mt][1] = __builtin_amdgcn_mfma_f32_16x16x32_f16(af, bf1, acc[mt][1], 0, 0, 0);
    }
    c0a = p0a; c0b = p0b; c1a = p1a; c1b = p1b;
  }

  // C/D layout: col = lane&15 (gate within 16-tile), row = q*4+r (bt within 16-tile)
#pragma unroll
  for (int mt = 0; mt < 4; ++mt) {
    const int bt = wv * 64 + mt * 16 + q * 4;
#pragma unroll
    for (int nt = 0; nt < 2; ++nt) {
      const int j = j0 + nt * 16 + i16;
#pragma unroll
      for (int r = 0; r < 4; ++r)
        p.partial[(size_t)kc * 65536 + (size_t)(bt + r) * G4_ + j] = acc[mt][nt][r];
    }
  }
}

// ---------------- phase: reduce split-K partials ----------------
__device__ __forceinline__ void ph_reduce(const KParams& p) {
  const int gs = gridDim.x * 256;
  for (int o = blockIdx.x * 256 + threadIdx.x; o < G4_ * BT_; o += gs) {
    float s0 = 0.f, s1 = 0.f, s2 = 0.f, s3 = 0.f;
#pragma unroll
    for (int kc = 0; kc < KC_; kc += 4) {
      s0 += p.partial[(size_t)(kc + 0) * 65536 + o];
      s1 += p.partial[(size_t)(kc + 1) * 65536 + o];
      s2 += p.partial[(size_t)(kc + 2) * 65536 + o];
      s3 += p.partial[(size_t)(kc + 3) * 65536 + o];
    }
    p.pre_gates[o] = (s0 + s1) + (s2 + s3);
  }
}

// ---------------- phase: LSTM recurrence for batch b ----------------
__device__ __forceinline__ void ph_lstm(const KParams& p, int b) {
  __shared__ float h_s[H_];
  __shared__ float g_s[G4_];
  const int tid = threadIdx.x;

  float wr[H_];
#pragma unroll
  for (int k = 0; k < H_; ++k) wr[k] = p.W_hh[(size_t)tid * H_ + k];
  float pg[S_];
#pragma unroll
  for (int t = 0; t < S_; ++t) pg[t] = p.pre_gates[(size_t)(b * S_ + t) * G4_ + tid];

  const float bias = p.b_ih[tid] + p.b_hh[tid];
  if (tid < H_) h_s[tid] = 0.f;
  float c = 0.f;
  __syncthreads();

  for (int t = 0; t < S_; ++t) {
    float g0 = pg[t] + bias, g1 = 0.f, g2 = 0.f, g3 = 0.f;
#pragma unroll
    for (int k = 0; k < H_; k += 4) {
      g0 = fmaf(wr[k + 0], h_s[k + 0], g0);
      g1 = fmaf(wr[k + 1], h_s[k + 1], g1);
      g2 = fmaf(wr[k + 2], h_s[k + 2], g2);
      g3 = fmaf(wr[k + 3], h_s[k + 3], g3);
    }
    g_s[tid] = (g0 + g1) + (g2 + g3);
    __syncthreads();
    if (tid < H_) {
      const float ig = fsigmoid(g_s[tid]);
      const float fg = fsigmoid(g_s[H_ + tid]);
      const float gg = ftanh_(g_s[2 * H_ + tid]);
      const float og = fsigmoid(g_s[3 * H_ + tid]);
      c = fg * c + ig * gg;
      h_s[tid] = og * ftanh_(c);
    }
    __syncthreads();
  }
  if (tid < H_) p.hT[b * H_ + tid] = h_s[tid];
}

// ---------------- phase: head ----------------
__device__ __forceinline__ void ph_head(const KParams& p) {
  const int gs = gridDim.x * 256;
  for (int o = blockIdx.x * 256 + threadIdx.x; o < B_ * N_; o += gs) {
    const int b = o / N_;
    const int n = o - b * N_;
    const float4* w4 = (const float4*)(p.W_head + (size_t)n * H_);
    const float4* h4 = (const float4*)(p.hT + (size_t)b * H_);
    float acc = p.b_head[n];
#pragma unroll
    for (int qq = 0; qq < H_ / 4; ++qq) {
      const float4 w = w4[qq];
      const float4 h = h4[qq];
      acc += w.x * h.x + w.y * h.y + w.z * h.z + w.w * h.w;
    }
    p.out[o] = acc;
  }
}

// ---------------- the cooperative mega-kernel ----------------
__global__ __launch_bounds__(256, 1) void mega_kernel(KParams p) {
  cg::grid_group grid = cg::this_grid();
  ph_zero(p);
  ph_transpose(p);
  grid.sync();
  ph_hist(p);
  grid.sync();
  if (blockIdx.x == 0) ph_scan(p);
  grid.sync();
  ph_scatter(p);
  grid.sync();
  ph_gather(p);
  grid.sync();
  ph_mfma(p, blockIdx.x);
  grid.sync();
  ph_reduce(p);
  grid.sync();
  if (blockIdx.x < B_) ph_lstm(p, blockIdx.x);
  grid.sync();
  ph_head(p);
}

// ---------------- fallback wrappers (used only if coop launch fails) ------
__global__ __launch_bounds__(256, 1) void k_pre(KParams p)     { ph_zero(p); ph_transpose(p); }
__global__ __launch_bounds__(256, 1) void k_hist(KParams p)    { ph_hist(p); }
__global__ __launch_bounds__(256, 1) void k_scan(KParams p)    { ph_scan(p); }
__global__ __launch_bounds__(256, 1) void k_scatter(KParams p) { ph_scatter(p); }
__global__ __launch_bounds__(256, 1) void k_gather(KParams p)  { ph_gather(p); }
__global__ __launch_bounds__(256, 1) void k_mfma(KParams p)    { ph_mfma(p, blockIdx.x); }
__global__ __launch_bounds__(256, 1) void k_reduce(KParams p)  { ph_reduce(p); }
__global__ __launch_bounds__(256, 1) void k_lstm(KParams p)    { ph_lstm(p, blockIdx.x); }
__global__ __launch_bounds__(256, 1) void k_head(KParams p)    { ph_head(p); }

// ---------------------------------------------------------------------------
extern "C" void kernel_launch(void* const* d_in, const int* in_sizes, int n_in,
                              void* d_out, int out_size, void* d_ws, size_t ws_size,
                              hipStream_t stream) {
  char* ws = (char*)d_ws;
  KParams p;
  p.x        = (const float*)d_in[0];
  p.ei       = (const int*)  d_in[1];
  p.w_lin    = (const float*)d_in[2];
  p.att_src  = (const float*)d_in[3];
  p.att_dst  = (const float*)d_in[4];
  p.gat_bias = (const float*)d_in[5];
  p.W_ih     = (const float*)d_in[6];
  p.W_hh     = (const float*)d_in[7];
  p.b_ih     = (const float*)d_in[8];
  p.b_hh     = (const float*)d_in[9];
  p.W_head   = (const float*)d_in[10];
  p.b_head   = (const float*)d_in[11];
  p.out      = (float*)d_out;
  p.xT        = (float*)(ws + 0);            // 2,048,000
  p.agg       = (float*)(ws + 2048000);      // 2,048,000
  p.pre_gates = (float*)(ws + 4096000);      //   262,144
  p.hT        = (float*)(ws + 4358144);      //     2,048
  p.deg       = (int*)  (ws + 4360192);      //     8,192
  p.rowptr    = (int*)  (ws + 4368384);      //     8,192
  p.cursor    = (int*)  (ws + 4376576);      //     8,192
  p.csr_src   = (int*)  (ws + 4384768);      //   256,000
  p.partial   = (float*)(ws + 4640768);      // 32*65536*4 = 8,388,608  -> ~13.0 MB total

  dim3 grid(256), block(256);
  void* args[] = { &p };
  hipError_t err = hipLaunchCooperativeKernel((void*)mega_kernel, grid, block, args, 0, stream);
  if (err != hipSuccess) {
    // deterministic fallback: same phases as ordinary dispatches
    k_pre<<<dim3(256), dim3(256), 0, stream>>>(p);
    k_hist<<<dim3(256), dim3(256), 0, stream>>>(p);
    k_scan<<<dim3(1), dim3(256), 0, stream>>>(p);
    k_scatter<<<dim3(256), dim3(256), 0, stream>>>(p);
    k_gather<<<dim3(2000), dim3(256), 0, stream>>>(p);
    k_mfma<<<dim3(256), dim3(256), 0, stream>>>(p);
    k_reduce<<<dim3(256), dim3(256), 0, stream>>>(p);
    k_lstm<<<dim3(B_), dim3(256), 0, stream>>>(p);
    k_head<<<dim3(256), dim3(256), 0, stream>>>(p);
  }
}

// Round 6
// 261.457 us; speedup vs baseline: 1.9966x; 1.9966x over previous
//
#include <hip/hip_runtime.h>
#include <hip/hip_bf16.h>
#include <cstddef>
#include <cstdint>

#define B_  8
#define S_  32
#define BT_ 256      // B*S
#define N_  2000
#define E_  64000
#define GH_ 32
#define H_  64
#define G4_ 256      // 4*H
#define D_  64000    // N*GH
#define NEG_SLOPE_ 0.2f
#define KC_  64      // split-K chunks; grid = 8 gate-blocks x 64 = 512 blocks

typedef __attribute__((ext_vector_type(8))) _Float16 half8;
typedef __attribute__((ext_vector_type(4))) float floatx4;

__device__ __forceinline__ float fsigmoid(float x) { return 1.0f / (1.0f + __expf(-x)); }
__device__ __forceinline__ float ftanh_(float x)   { return 1.0f - 2.0f / (__expf(2.0f * x) + 1.0f); }

// ---------------------------------------------------------------------------
// K1: zero deg + transpose x [bt][n] -> xT [n][bt]. grid 504.
// ---------------------------------------------------------------------------
__global__ __launch_bounds__(256) void k_prep(
    const float* __restrict__ x, float* __restrict__ xT, int* __restrict__ deg)
{
  const int gt = blockIdx.x * 256 + threadIdx.x;
  if (gt < N_) deg[gt] = 0;

  __shared__ float tile[32][33];
  const int TXT = (N_ + 31) / 32;  // 63
  const int t = blockIdx.x;
  if (t >= TXT * (BT_ / 32)) return;
  const int tx = threadIdx.x & 31;
  const int ty = threadIdx.x >> 5;
  const int n0  = (t % TXT) * 32;
  const int bt0 = (t / TXT) * 32;
#pragma unroll
  for (int r = 0; r < 4; ++r) {
    const int bt = bt0 + ty + r * 8;
    const int nn = n0 + tx;
    if (nn < N_) tile[ty + r * 8][tx] = x[(size_t)bt * N_ + nn];
  }
  __syncthreads();
#pragma unroll
  for (int r = 0; r < 4; ++r) {
    const int n = n0 + ty + r * 8;
    if (n < N_) xT[(size_t)n * BT_ + bt0 + tx] = tile[tx][ty + r * 8];
  }
}

// ---------------------------------------------------------------------------
// K2: degree histogram by dst. grid 250.
// ---------------------------------------------------------------------------
__global__ __launch_bounds__(256) void k_hist(
    const int* __restrict__ ei, int* __restrict__ deg)
{
  const int i = blockIdx.x * 256 + threadIdx.x;
  if (i < E_) atomicAdd(&deg[ei[E_ + i]], 1);
}

// ---------------------------------------------------------------------------
// K3: exclusive scan deg -> rowptr + cursor. 1 block.
// ---------------------------------------------------------------------------
__global__ __launch_bounds__(256) void k_scan(
    const int* __restrict__ deg, int* __restrict__ rowptr, int* __restrict__ cursor)
{
  __shared__ int tsum[256];
  const int tid = threadIdx.x;
  int v[8];
  int s = 0;
  const int base = tid * 8;
#pragma unroll
  for (int j = 0; j < 8; ++j) {
    const int idx = base + j;
    const int d = (idx < N_) ? deg[idx] : 0;
    v[j] = s;
    s += d;
  }
  tsum[tid] = s;
  __syncthreads();
  for (int off = 1; off < 256; off <<= 1) {
    int t = 0;
    if (tid >= off) t = tsum[tid - off];
    __syncthreads();
    tsum[tid] += t;
    __syncthreads();
  }
  const int ebase = tsum[tid] - s;
#pragma unroll
  for (int j = 0; j < 8; ++j) {
    const int idx = base + j;
    if (idx < N_) {
      const int r = ebase + v[j];
      rowptr[idx] = r;
      cursor[idx] = r;
    }
  }
  if (tid == 0) rowptr[N_] = E_;
}

// ---------------------------------------------------------------------------
// K4: scatter src ids into CSR buckets. grid 250.
// ---------------------------------------------------------------------------
__global__ __launch_bounds__(256) void k_scatter(
    const int* __restrict__ ei, int* __restrict__ cursor, int* __restrict__ csr_src)
{
  const int i = blockIdx.x * 256 + threadIdx.x;
  if (i >= E_) return;
  const int s = ei[i];
  const int d = ei[E_ + i];
  const int pos = atomicAdd(&cursor[d], 1);
  csr_src[pos] = s;
}

// ---------------------------------------------------------------------------
// K5: CSR gather-aggregate -> agg fp32 [n][bt]. One block per node (2000).
// agg = (sum_in exp(e)*x_src + exp(e_self)*x_n) / (sum exp)
// 4-wide unroll keeps 4 independent L2 row-loads in flight; csr reads are
// wave-uniform -> scalar loads.
// ---------------------------------------------------------------------------
__global__ __launch_bounds__(256) void k_gather(
    const float* __restrict__ xT, const int* __restrict__ rowptr,
    const int* __restrict__ csr_src,
    const float* __restrict__ w_lin, const float* __restrict__ att_src,
    const float* __restrict__ att_dst, float* __restrict__ agg)
{
  const int n   = blockIdx.x;
  const int tid = threadIdx.x;
  float c_s = 0.f, c_d = 0.f;
  for (int g = 0; g < GH_; ++g) {
    const float w = w_lin[g];
    c_s += w * att_src[g];
    c_d += w * att_dst[g];
  }
  const int r0 = rowptr[n];
  const int d  = rowptr[n + 1] - r0;
  const float xn = xT[(size_t)n * BT_ + tid];
  const float cdxn = c_d * xn;
  float e = (c_s + c_d) * xn;
  e = e > 0.f ? e : NEG_SLOPE_ * e;
  const float w0 = __expf(e);
  float num = w0 * xn, den = w0;
  int pp = 0;
  for (; pp + 4 <= d; pp += 4) {
    const int s0 = csr_src[r0 + pp + 0];
    const int s1 = csr_src[r0 + pp + 1];
    const int s2 = csr_src[r0 + pp + 2];
    const int s3 = csr_src[r0 + pp + 3];
    const float x0 = xT[(size_t)s0 * BT_ + tid];
    const float x1 = xT[(size_t)s1 * BT_ + tid];
    const float x2 = xT[(size_t)s2 * BT_ + tid];
    const float x3 = xT[(size_t)s3 * BT_ + tid];
    float e0 = fmaf(c_s, x0, cdxn); e0 = e0 > 0.f ? e0 : NEG_SLOPE_ * e0;
    float e1 = fmaf(c_s, x1, cdxn); e1 = e1 > 0.f ? e1 : NEG_SLOPE_ * e1;
    float e2 = fmaf(c_s, x2, cdxn); e2 = e2 > 0.f ? e2 : NEG_SLOPE_ * e2;
    float e3 = fmaf(c_s, x3, cdxn); e3 = e3 > 0.f ? e3 : NEG_SLOPE_ * e3;
    const float w0_ = __expf(e0), w1_ = __expf(e1), w2_ = __expf(e2), w3_ = __expf(e3);
    num += w0_ * x0 + w1_ * x1 + w2_ * x2 + w3_ * x3;
    den += (w0_ + w1_) + (w2_ + w3_);
  }
  for (; pp < d; ++pp) {
    const int s = csr_src[r0 + pp];
    const float xs = xT[(size_t)s * BT_ + tid];
    float ee = fmaf(c_s, xs, cdxn);
    ee = ee > 0.f ? ee : NEG_SLOPE_ * ee;
    const float ww = __expf(ee);
    num += ww * xs;
    den += ww;
  }
  agg[(size_t)n * BT_ + tid] = num / den;
}

// ---------------------------------------------------------------------------
// K6: fp16 MFMA matmul, in-register A-expansion, split-K.
// pre_gates[bt,j] = sum_{n,gh} W_ih[j, n*32+gh] * relu(agg[bt,n]*wl[gh]+gb[gh])
// grid (8 nb, 64 kc); block 256 = 4 waves; wave = M64 x N32 (4x2 16-tiles).
// W_ih read exactly once; agg (2 MB) L2-resident; partial 16.8 MB.
// ---------------------------------------------------------------------------
__global__ __launch_bounds__(256) void k_mfma(
    const float* __restrict__ W_ih, const float* __restrict__ agg,
    const float* __restrict__ w_lin, const float* __restrict__ gat_bias,
    float* __restrict__ partial)
{
  const int nb = blockIdx.x;       // 0..7  -> j in [nb*32, nb*32+32)
  const int kc = blockIdx.y;       // 0..63
  const int n0 = (N_ * kc) / KC_;
  const int n1 = (N_ * (kc + 1)) / KC_;
  const int tid  = threadIdx.x;
  const int wv   = tid >> 6;
  const int lane = tid & 63;
  const int i16  = lane & 15;
  const int q    = lane >> 4;
  const int j0   = nb * 32;

  float wlq[8], gbq[8];
#pragma unroll
  for (int j = 0; j < 8; ++j) {
    wlq[j] = w_lin[q * 8 + j];
    gbq[j] = gat_bias[q * 8 + j];
  }

  floatx4 acc[4][2];
#pragma unroll
  for (int mt = 0; mt < 4; ++mt)
#pragma unroll
    for (int nt = 0; nt < 2; ++nt)
#pragma unroll
      for (int r = 0; r < 4; ++r) acc[mt][nt][r] = 0.f;

  const float* Bp0 = W_ih + (size_t)(j0 + i16) * D_ + (size_t)n0 * GH_ + q * 8;
  const float* Bp1 = Bp0 + (size_t)16 * D_;

  float4 c0a = *(const float4*)(Bp0);
  float4 c0b = *(const float4*)(Bp0 + 4);
  float4 c1a = *(const float4*)(Bp1);
  float4 c1b = *(const float4*)(Bp1 + 4);

#pragma unroll 1
  for (int nn = n0; nn < n1; ++nn) {
    // prefetch next node's B fragment
    const int nx = (nn + 1 < n1) ? (nn + 1 - n0) : (nn - n0);
    const int off = nx * GH_;
    float4 p0a = *(const float4*)(Bp0 + off);
    float4 p0b = *(const float4*)(Bp0 + off + 4);
    float4 p1a = *(const float4*)(Bp1 + off);
    float4 p1b = *(const float4*)(Bp1 + off + 4);

    half8 bf0, bf1;
    bf0[0] = (_Float16)c0a.x; bf0[1] = (_Float16)c0a.y;
    bf0[2] = (_Float16)c0a.z; bf0[3] = (_Float16)c0a.w;
    bf0[4] = (_Float16)c0b.x; bf0[5] = (_Float16)c0b.y;
    bf0[6] = (_Float16)c0b.z; bf0[7] = (_Float16)c0b.w;
    bf1[0] = (_Float16)c1a.x; bf1[1] = (_Float16)c1a.y;
    bf1[2] = (_Float16)c1a.z; bf1[3] = (_Float16)c1a.w;
    bf1[4] = (_Float16)c1b.x; bf1[5] = (_Float16)c1b.y;
    bf1[6] = (_Float16)c1b.z; bf1[7] = (_Float16)c1b.w;

    const float* Ar = agg + (size_t)nn * BT_ + wv * 64 + i16;
#pragma unroll
    for (int mt = 0; mt < 4; ++mt) {
      const float a = Ar[mt * 16];
      half8 af;
#pragma unroll
      for (int j = 0; j < 8; ++j) {
        float v = fmaf(a, wlq[j], gbq[j]);
        v = fmaxf(v, 0.f);
        af[j] = (_Float16)v;
      }
      acc[mt][0] = __builtin_amdgcn_mfma_f32_16x16x32_f16(af, bf0, acc[mt][0], 0, 0, 0);
      acc[mt][1] = __builtin_amdgcn_mfma_f32_16x16x32_f16(af, bf1, acc[mt][1], 0, 0, 0);
    }
    c0a = p0a; c0b = p0b; c1a = p1a; c1b = p1b;
  }

  // C/D layout: col = lane&15 (gate), row = q*4+r (bt within 16-tile)
#pragma unroll
  for (int mt = 0; mt < 4; ++mt) {
    const int bt = wv * 64 + mt * 16 + q * 4;
#pragma unroll
    for (int nt = 0; nt < 2; ++nt) {
      const int j = j0 + nt * 16 + i16;
#pragma unroll
      for (int r = 0; r < 4; ++r)
        partial[(size_t)kc * 65536 + (size_t)(bt + r) * G4_ + j] = acc[mt][nt][r];
    }
  }
}

// ---------------------------------------------------------------------------
// K7: reduce split-K partials -> pre_gates. grid 256.
// ---------------------------------------------------------------------------
__global__ __launch_bounds__(256) void k_reduce(
    const float* __restrict__ partial, float* __restrict__ pre_gates)
{
  const int o = blockIdx.x * 256 + threadIdx.x;
  float s0 = 0.f, s1 = 0.f, s2 = 0.f, s3 = 0.f;
#pragma unroll
  for (int kc = 0; kc < KC_; kc += 4) {
    s0 += partial[(size_t)(kc + 0) * 65536 + o];
    s1 += partial[(size_t)(kc + 1) * 65536 + o];
    s2 += partial[(size_t)(kc + 2) * 65536 + o];
    s3 += partial[(size_t)(kc + 3) * 65536 + o];
  }
  pre_gates[o] = (s0 + s1) + (s2 + s3);
}

// ---------------------------------------------------------------------------
// K8: LSTM recurrence + head, one block per batch b (8 blocks).
// ---------------------------------------------------------------------------
__global__ __launch_bounds__(256) void k_lstm_head(
    const float* __restrict__ pre_gates, const float* __restrict__ W_hh,
    const float* __restrict__ b_ih, const float* __restrict__ b_hh,
    const float* __restrict__ W_head, const float* __restrict__ b_head,
    float* __restrict__ out)
{
  const int b   = blockIdx.x;
  const int tid = threadIdx.x;
  __shared__ float h_s[H_];
  __shared__ float g_s[G4_];

  float wr[H_];
#pragma unroll
  for (int k = 0; k < H_; ++k) wr[k] = W_hh[(size_t)tid * H_ + k];
  float pg[S_];
#pragma unroll
  for (int t = 0; t < S_; ++t) pg[t] = pre_gates[(size_t)(b * S_ + t) * G4_ + tid];

  const float bias = b_ih[tid] + b_hh[tid];
  if (tid < H_) h_s[tid] = 0.f;
  float c = 0.f;
  __syncthreads();

  for (int t = 0; t < S_; ++t) {
    float g0 = pg[t] + bias, g1 = 0.f, g2 = 0.f, g3 = 0.f;
#pragma unroll
    for (int k = 0; k < H_; k += 4) {
      g0 = fmaf(wr[k + 0], h_s[k + 0], g0);
      g1 = fmaf(wr[k + 1], h_s[k + 1], g1);
      g2 = fmaf(wr[k + 2], h_s[k + 2], g2);
      g3 = fmaf(wr[k + 3], h_s[k + 3], g3);
    }
    g_s[tid] = (g0 + g1) + (g2 + g3);
    __syncthreads();
    if (tid < H_) {
      const float ig = fsigmoid(g_s[tid]);
      const float fg = fsigmoid(g_s[H_ + tid]);
      const float gg = ftanh_(g_s[2 * H_ + tid]);
      const float og = fsigmoid(g_s[3 * H_ + tid]);
      c = fg * c + ig * gg;
      h_s[tid] = og * ftanh_(c);
    }
    __syncthreads();
  }

  for (int n = tid; n < N_; n += 256) {
    const float4* w4 = (const float4*)(W_head + (size_t)n * H_);
    float acc = b_head[n];
#pragma unroll
    for (int qq = 0; qq < H_ / 4; ++qq) {
      const float4 w = w4[qq];
      acc += w.x * h_s[qq * 4 + 0] + w.y * h_s[qq * 4 + 1] +
             w.z * h_s[qq * 4 + 2] + w.w * h_s[qq * 4 + 3];
    }
    out[(size_t)b * N_ + n] = acc;
  }
}

// ---------------------------------------------------------------------------
extern "C" void kernel_launch(void* const* d_in, const int* in_sizes, int n_in,
                              void* d_out, int out_size, void* d_ws, size_t ws_size,
                              hipStream_t stream) {
  const float* x        = (const float*)d_in[0];
  const int*   ei       = (const int*)  d_in[1];
  const float* w_lin    = (const float*)d_in[2];
  const float* att_src  = (const float*)d_in[3];
  const float* att_dst  = (const float*)d_in[4];
  const float* gat_bias = (const float*)d_in[5];
  const float* W_ih     = (const float*)d_in[6];
  const float* W_hh     = (const float*)d_in[7];
  const float* b_ih     = (const float*)d_in[8];
  const float* b_hh     = (const float*)d_in[9];
  const float* W_head   = (const float*)d_in[10];
  const float* b_head   = (const float*)d_in[11];
  float* out = (float*)d_out;

  char* ws = (char*)d_ws;
  float* xT        = (float*)(ws + 0);          //  2,048,000
  float* agg       = (float*)(ws + 2048000);    //  2,048,000
  float* pre_gates = (float*)(ws + 4096000);    //    262,144
  int*   deg       = (int*)  (ws + 4358144);    //      8,192
  int*   rowptr    = (int*)  (ws + 4366336);    //      8,192
  int*   cursor    = (int*)  (ws + 4374528);    //      8,192
  int*   csr_src   = (int*)  (ws + 4382720);    //    256,000
  float* partial   = (float*)(ws + 4638720);    // 64*65536*4 = 16,777,216 -> 21.4 MB total

  k_prep<<<dim3(504), dim3(256), 0, stream>>>(x, xT, deg);
  k_hist<<<dim3((E_ + 255) / 256), dim3(256), 0, stream>>>(ei, deg);
  k_scan<<<dim3(1), dim3(256), 0, stream>>>(deg, rowptr, cursor);
  k_scatter<<<dim3((E_ + 255) / 256), dim3(256), 0, stream>>>(ei, cursor, csr_src);
  k_gather<<<dim3(N_), dim3(256), 0, stream>>>(
      xT, rowptr, csr_src, w_lin, att_src, att_dst, agg);
  k_mfma<<<dim3(8, KC_), dim3(256), 0, stream>>>(
      W_ih, agg, w_lin, gat_bias, partial);
  k_reduce<<<dim3(256), dim3(256), 0, stream>>>(partial, pre_gates);
  k_lstm_head<<<dim3(B_), dim3(256), 0, stream>>>(
      pre_gates, W_hh, b_ih, b_hh, W_head, b_head, out);
}